// Round 15
// baseline (428.875 us; speedup 1.0000x reference)
//
#include <hip/hip_runtime.h>
#include <math.h>

// VIN forward on MI355X — 256 WGs x 512 thr (8 waves): WG = half-image.
// Sizes: N=128, H=W=64, CH_I=2, CH_H=150, CH_Q=10, N_ACT=8, VInum=36.
//
// R24 -> R25: resurrect the 2-WG-per-image split (kill the idle half-chip).
//  R15's 11us/iter exchange cost was a flag COHERENCE STORM (256 flags in
//  16 shared cache lines, 16 cross-XCD writers/line invalidating all
//  spinners), not intrinsic latency. Fixes: (1) every flag in a private
//  128B line; (2) only ONE 64-float boundary row crosses WGs per iter (the
//  DPP layout needs only the half-boundary, not per-wave rows); (3) publish
//  = relaxed stores + wave-wide threadfence + single-lane flag store;
//  (4) only the boundary wave spins (overlapped by the peer's intra-WG
//  barrier); pairs XCD-swizzled -> one L2. Intra-WG K-loop = R19 verbatim
//  (DPP horizontal, vprev vertical, exT/exB edge rows, s_load weights,
//  4 rows/thread). Prologue/epilogue = R15's verified split form.
//  Per-CU/iter: VALU 0.4us (halved), SQC 360 s_loads (halved), 8-wave
//  barrier, exchange ~0.25us mostly hidden. All FP orders unchanged ->
//  bit-identical (ghost rows are the same register floats the unified
//  version stored; r ghost rows recomputed locally with identical
//  formula/order). 256 WGs co-resident (50KB LDS, 8 waves) -> no deadlock.

typedef float v2f __attribute__((ext_vector_type(2)));

static __device__ __forceinline__ v2f splat2(float s) { v2f r; r.x = s; r.y = s; return r; }
static __device__ __forceinline__ v2f pkfma(v2f w, float v, v2f a) {
#if __has_builtin(__builtin_elementwise_fma)
    return __builtin_elementwise_fma(w, splat2(v), a);
#else
    v2f r; r.x = fmaf(w.x, v, a.x); r.y = fmaf(w.y, v, a.y); return r;
#endif
}
static __device__ __forceinline__ v2f pkmax(v2f a, v2f b) {
#if __has_builtin(__builtin_elementwise_max)
    return __builtin_elementwise_max(a, b);
#else
    v2f r; r.x = fmaxf(a.x, b.x); r.y = fmaxf(a.y, b.y); return r;
#endif
}

#define DPP_SHR1 0x138   // lane n <- lane n-1  (left-neighbor value)
#define DPP_SHL1 0x130   // lane n <- lane n+1  (right-neighbor value)
template <int CTRL>
static __device__ __forceinline__ float dppsh(float v) {
    return __int_as_float(__builtin_amdgcn_update_dpp(
        0, __float_as_int(v), CTRL, 0xF, 0xF, false));
}

#define XROW 69
#define VROW 67
#define XS_ROWS 38               // x rows s-3 .. s+34
#define RS_ROWS 34               // r rows s-1 .. s+32 (storage ri = local+1)

__global__ void
__attribute__((amdgpu_flat_work_group_size(512, 512)))
__attribute__((amdgpu_waves_per_eu(2, 2)))
vin_kernel(const float* __restrict__ x,
           const int* __restrict__ S1,
           const int* __restrict__ S2,
           const int* __restrict__ VInum,
           const float* __restrict__ w0,
           const float* __restrict__ b0,
           const float* __restrict__ w_r,
           const float* __restrict__ w_q,
           const float* __restrict__ w_sw,
           const float* __restrict__ w_sw2,
           const float* __restrict__ w_dense,
           float* __restrict__ out,
           void* __restrict__ ws) {
    const int g = blockIdx.x;
    const int t = threadIdx.x;
    // XCD-pair swizzle (perf-only): both halves of an image on one XCD.
    const int xcd  = g & 7;
    const int slot = g >> 3;                   // 0..31
    const int b    = xcd * 16 + (slot >> 1);   // image 0..127
    const int h    = slot & 1;                 // 0 = rows 0..31, 1 = rows 32..63
    const int s    = h << 5;

    // ws layout: flags (each in a private 128B line), then halo rows.
    int*   F   = (int*)ws;                     // F[(b*2+dir)*32], dir0=Hdn, dir1=Hup
    float* Hdn = (float*)ws + 8192;            // [128][2][64]: h0's row 31
    float* Hup = Hdn + 128 * 2 * 64;           // [128][2][64]: h1's row 32
    int* Fdn = &F[(b * 2 + 0) * 32];
    int* Fup = &F[(b * 2 + 1) * 32];

    __shared__ float xs0[XS_ROWS * XROW];  // x ch0, 2-col zero halo
    __shared__ float xs1[XS_ROWS * XROW];  // x ch1
    __shared__ float rs[RS_ROWS * VROW];   // r rows s-1..s+32, 1-col zero halo
    __shared__ float wtA[1620];            // P chunk partials
    __shared__ float Pp[450];              // zero-init
    __shared__ float Bt[90];
    __shared__ float Bv[9];
    __shared__ float W5c[459];
    __shared__ float exT[2][9][64];        // wave top-row edge, by parity (slot 8 = 0)
    __shared__ float exB[2][9][64];        // wave bottom-row edge, by parity
    __shared__ float qsel[10];

    // ---- zero LDS ----
    for (int i = t; i < XS_ROWS * XROW; i += 512) { xs0[i] = 0.f; xs1[i] = 0.f; }
    for (int i = t; i < RS_ROWS * VROW; i += 512) rs[i] = 0.f;
    for (int i = t; i < 2 * 9 * 64; i += 512) {
        ((float*)exT)[i] = 0.f; ((float*)exB)[i] = 0.f;
    }
    if (t < 450) Pp[t] = 0.f;
    __syncthreads();

    // ---- stage x rows s-3..s+34 (clipped) [R15-verified] ----
    for (int i = t; i < XS_ROWS * 32; i += 512) {
        int xl = i >> 5, grp = i & 31;
        int gx = s - 3 + xl;
        if (gx < 0 || gx > 63) continue;
        float4 v4 = *(const float4*)(x + ((size_t)(b * 64 + gx) * 64 + grp * 2) * 2);
        int px = grp * 2;
        xs0[xl * XROW + px + 2] = v4.x; xs1[xl * XROW + px + 2] = v4.y;
        xs0[xl * XROW + px + 3] = v4.z; xs1[xl * XROW + px + 3] = v4.w;
    }
    // ---- round A [R15-verified] ----
    for (int idx = t; idx < 1620; idx += 512) {
        int entry = idx / 10, ch = idx - entry * 10;
        int d = entry / 18, rem = entry % 18;
        int uu = rem >> 1, ci = rem & 1;
        int c0 = ch * 15;
        const float* wr = w_r + d * 150;
        const float* wp = w0 + (uu * 2 + ci) * 150;
        float ssum = 0.f;
        for (int c = c0; c < c0 + 15; ++c) ssum += wr[c] * wp[c];
        wtA[idx] = ssum;
    }
    if (t < 90) {
        int d = t / 10, ch = t - d * 10, c0 = ch * 15;
        float ssum = 0.f;
        for (int c = c0; c < c0 + 15; ++c) ssum += w_r[d * 150 + c] * b0[c];
        Bt[t] = ssum;
    }
    __syncthreads();
    // ---- round B [R15-verified] ----
    if (t < 162) {
        float ssum = 0.f;
        #pragma unroll
        for (int i = 0; i < 10; ++i) ssum += wtA[t * 10 + i];
        int d = t / 18, rem = t % 18;
        int uu = rem >> 1, ci = rem & 1;
        int dy = d / 3 - 1, dx = d % 3 - 1;
        int uy = uu / 3 - 1, ux = uu % 3 - 1;
        int eidx = (dy + uy + 2) * 5 + (dx + ux + 2);
        Pp[d * 50 + eidx * 2 + ci] = ssum;
    } else if (t >= 256 && t < 265) {
        int d = t - 256;
        float ssum = 0.f;
        #pragma unroll
        for (int i = 0; i < 10; ++i) ssum += Bt[d * 10 + i];
        Bv[d] = ssum;
    }
    __syncthreads();
    // ---- round C [R15-verified] ----
    if (t < 459) {
        int cls = t / 51, j = t - cls * 51;
        int cy = cls / 3, cx = cls % 3;
        float ssum = 0.f;
        #pragma unroll
        for (int d = 0; d < 9; ++d) {
            int dy = d / 3 - 1, dx = d % 3 - 1;
            bool ok = (cy == 0 || (cy == 1 ? dy >= 0 : dy <= 0)) &&
                      (cx == 0 || (cx == 1 ? dx >= 0 : dx <= 0));
            if (ok) ssum += (j < 50) ? Pp[d * 50 + j] : Bv[d];
        }
        W5c[t] = ssum;
    }
    __syncthreads();

    // ---- r for rows s-1..s+32 (34 rows) [R15-verified] ----
    for (int i = t; i < RS_ROWS * 64; i += 512) {
        int ri = i >> 6;
        int c  = i & 63;
        int gy = s + ri - 1;
        if (gy < 0 || gy > 63) continue;
        int cy = (gy == 0) ? 1 : (gy == 63) ? 2 : 0;
        int cx = (c == 0) ? 1 : (c == 63) ? 2 : 0;
        const float* Wp = &W5c[(cy * 3 + cx) * 51];
        float acc = Wp[50];
        #pragma unroll
        for (int e = 0; e < 25; ++e) {
            int xi = (ri + e / 5) * XROW + (c + e % 5);
            acc = fmaf(xs0[xi], Wp[e * 2], acc);
            acc = fmaf(xs1[xi], Wp[e * 2 + 1], acc);
        }
        rs[ri * VROW + (c + 1)] = acc;
    }
    __syncthreads();

    // ============ column-per-lane mapping ============
    const int c   = t & 63;          // column 0..63 (lane)
    const int w   = t >> 6;          // wave 0..7, owns local rows 4w..4w+3
    const int lr0 = w << 2;
    const int upSlot = (w == 0) ? 8 : w - 1;
    const int dnSlot = (w == 7) ? 8 : w + 1;
    const bool ghostTop = (h == 1 && w == 0);  // reads Hdn, publishes Hup
    const bool ghostBot = (h == 0 && w == 7);  // reads Hup, publishes Hdn
    const int K = VInum[0];

    // ---- Rsw precompute + v^1 (w_q), r window via DPP ----
    v2f Rsw2[4][5];
    float vprev[4];
    float RC[6], RL[6], RR[6];
    #pragma unroll
    for (int j = 0; j < 6; ++j) RC[j] = rs[(lr0 + j) * VROW + c + 1];  // local rows lr0-1..lr0+4
    #pragma unroll
    for (int j = 0; j < 6; ++j) { RL[j] = dppsh<DPP_SHR1>(RC[j]); RR[j] = dppsh<DPP_SHL1>(RC[j]); }
    {
        float vmax[4];
        #pragma unroll
        for (int a = 0; a < 10; ++a) {
            #pragma unroll
            for (int i = 0; i < 4; ++i) {
                float accR = 0.f, accQ = 0.f;
                #pragma unroll
                for (int d = 0; d < 9; ++d) {
                    const int dy = d / 3, dx = d % 3;
                    const float rv = (dx == 0 ? RL : dx == 1 ? RC : RR)[i + dy];
                    accR = fmaf(w_sw[d * 20 + a], rv, accR);
                    accQ = fmaf(w_q[d * 20 + a],  rv, accQ);
                }
                if (a & 1) Rsw2[i][a >> 1].y = accR; else Rsw2[i][a >> 1].x = accR;
                vmax[i] = (a == 0) ? accQ : fmaxf(vmax[i], accQ);
            }
        }
        exT[1][w][c] = vmax[0];
        exB[1][w][c] = vmax[3];
        if (ghostBot) {   // h0 wave7: publish row 31 (v^1) -> Hdn slot 1
            __hip_atomic_store(&Hdn[(b * 2 + 1) * 64 + c], vmax[3],
                               __ATOMIC_RELAXED, __HIP_MEMORY_SCOPE_AGENT);
            __threadfence();
            if (c == 0) __hip_atomic_store(Fdn, 1, __ATOMIC_RELEASE, __HIP_MEMORY_SCOPE_AGENT);
        }
        if (ghostTop) {   // h1 wave0: publish row 32 (v^1) -> Hup slot 1
            __hip_atomic_store(&Hup[(b * 2 + 1) * 64 + c], vmax[0],
                               __ATOMIC_RELAXED, __HIP_MEMORY_SCOPE_AGENT);
            __threadfence();
            if (c == 0) __hip_atomic_store(Fup, 1, __ATOMIC_RELEASE, __HIP_MEMORY_SCOPE_AGENT);
        }
        #pragma unroll
        for (int i = 0; i < 4; ++i) vprev[i] = vmax[i];
    }
    __syncthreads();

    // ---- K-1 shared-weight VI steps: R19 K-loop + 1-row cross-WG ghost ----
    for (int k = 2; k <= K; ++k) {
        const int pr = (k - 1) & 1, pw = k & 1;
        float vTop, vBot;
        if (ghostTop) {
            while (__hip_atomic_load(Fdn, __ATOMIC_ACQUIRE, __HIP_MEMORY_SCOPE_AGENT) < k - 1) {}
            vTop = __hip_atomic_load(&Hdn[(b * 2 + pr) * 64 + c],
                                     __ATOMIC_RELAXED, __HIP_MEMORY_SCOPE_AGENT);
        } else {
            vTop = exB[pr][upSlot][c];
        }
        if (ghostBot) {
            while (__hip_atomic_load(Fup, __ATOMIC_ACQUIRE, __HIP_MEMORY_SCOPE_AGENT) < k - 1) {}
            vBot = __hip_atomic_load(&Hup[(b * 2 + pr) * 64 + c],
                                     __ATOMIC_RELAXED, __HIP_MEMORY_SCOPE_AGENT);
        } else {
            vBot = exT[pr][dnSlot][c];
        }
        float VC[6], VL[6], VR[6];
        VC[0] = vTop; VC[5] = vBot;
        #pragma unroll
        for (int i = 0; i < 4; ++i) VC[i + 1] = vprev[i];
        #pragma unroll
        for (int j = 0; j < 6; ++j) { VL[j] = dppsh<DPP_SHR1>(VC[j]); VR[j] = dppsh<DPP_SHL1>(VC[j]); }

        v2f acc[4][5];
        #pragma unroll
        for (int ap = 0; ap < 5; ++ap) {
            #pragma unroll
            for (int d = 0; d < 9; ++d) {
                v2f w2; w2.x = w_sw[d * 20 + 10 + 2 * ap]; w2.y = w_sw[d * 20 + 10 + 2 * ap + 1];
                const int dy = d / 3, dx = d % 3;
                const float* S = (dx == 0) ? VL : (dx == 1) ? VC : VR;
                #pragma unroll
                for (int i = 0; i < 4; ++i)
                    acc[i][ap] = (d == 0) ? pkfma(w2, S[i + dy], Rsw2[i][ap])
                                          : pkfma(w2, S[i + dy], acc[i][ap]);
            }
        }
        float vnew[4];
        #pragma unroll
        for (int i = 0; i < 4; ++i) {
            v2f m2 = acc[i][0];
            #pragma unroll
            for (int ap = 1; ap < 5; ++ap) m2 = pkmax(m2, acc[i][ap]);
            vnew[i] = fmaxf(m2.x, m2.y);
        }
        exT[pw][w][c] = vnew[0];
        exB[pw][w][c] = vnew[3];
        if (ghostBot) {
            __hip_atomic_store(&Hdn[(b * 2 + pw) * 64 + c], vnew[3],
                               __ATOMIC_RELAXED, __HIP_MEMORY_SCOPE_AGENT);
            __threadfence();
            if (c == 0) __hip_atomic_store(Fdn, k, __ATOMIC_RELEASE, __HIP_MEMORY_SCOPE_AGENT);
        }
        if (ghostTop) {
            __hip_atomic_store(&Hup[(b * 2 + pw) * 64 + c], vnew[0],
                               __ATOMIC_RELAXED, __HIP_MEMORY_SCOPE_AGENT);
            __threadfence();
            if (c == 0) __hip_atomic_store(Fup, k, __ATOMIC_RELEASE, __HIP_MEMORY_SCOPE_AGENT);
        }
        #pragma unroll
        for (int i = 0; i < 4; ++i) vprev[i] = vnew[i];
        __syncthreads();
    }

    // ---- final step with w_sw2: q -> global, gather (S1,S2) ----
    const int s1 = S1[b], s2 = S2[b];
    {
        const int pK = K & 1;
        float vTop, vBot;
        if (ghostTop) {
            while (__hip_atomic_load(Fdn, __ATOMIC_ACQUIRE, __HIP_MEMORY_SCOPE_AGENT) < K) {}
            vTop = __hip_atomic_load(&Hdn[(b * 2 + pK) * 64 + c],
                                     __ATOMIC_RELAXED, __HIP_MEMORY_SCOPE_AGENT);
        } else {
            vTop = exB[pK][upSlot][c];
        }
        if (ghostBot) {
            while (__hip_atomic_load(Fup, __ATOMIC_ACQUIRE, __HIP_MEMORY_SCOPE_AGENT) < K) {}
            vBot = __hip_atomic_load(&Hup[(b * 2 + pK) * 64 + c],
                                     __ATOMIC_RELAXED, __HIP_MEMORY_SCOPE_AGENT);
        } else {
            vBot = exT[pK][dnSlot][c];
        }
        float VC[6], VL[6], VR[6];
        VC[0] = vTop; VC[5] = vBot;
        #pragma unroll
        for (int i = 0; i < 4; ++i) VC[i + 1] = vprev[i];
        #pragma unroll
        for (int j = 0; j < 6; ++j) { VL[j] = dppsh<DPP_SHR1>(VC[j]); VR[j] = dppsh<DPP_SHL1>(VC[j]); }

        float qv[4][10];
        #pragma unroll
        for (int a = 0; a < 10; ++a) {
            #pragma unroll
            for (int i = 0; i < 4; ++i) {
                float acc = 0.f;
                #pragma unroll
                for (int d = 0; d < 9; ++d) {
                    const int dy = d / 3, dx = d % 3;
                    acc = fmaf(w_sw2[d * 20 + a],
                               (dx == 0 ? RL : dx == 1 ? RC : RR)[i + dy], acc);
                    acc = fmaf(w_sw2[d * 20 + 10 + a],
                               (dx == 0 ? VL : dx == 1 ? VC : VR)[i + dy], acc);
                }
                qv[i][a] = acc;
            }
        }
        // store q: 10 floats per px, 8B-aligned -> 5x float2 per row
        #pragma unroll
        for (int i = 0; i < 4; ++i) {
            float2* qp = (float2*)(out + 2048 +
                          ((size_t)((b * 64 + s + lr0 + i) * 64 + c)) * 10);
            #pragma unroll
            for (int gq = 0; gq < 5; ++gq)
                qp[gq] = make_float2(qv[i][2 * gq], qv[i][2 * gq + 1]);
        }
        if (c == s2) {
            #pragma unroll
            for (int i = 0; i < 4; ++i)
                if (s1 == s + lr0 + i) {
                    #pragma unroll
                    for (int a = 0; a < 10; ++a) qsel[a] = qv[i][a];
                }
        }
    }
    __syncthreads();

    // ---- dense + softmax + q_out (only the half owning row S1) ----
    if ((s1 >> 5) == h) {
        if (t == 0) {
            float logits[8];
            float m = -1e30f;
            #pragma unroll
            for (int j = 0; j < 8; ++j) {
                float ssum = 0.f;
                #pragma unroll
                for (int a = 0; a < 10; ++a) ssum += qsel[a] * w_dense[a * 8 + j];
                logits[j] = ssum;
                m = fmaxf(m, ssum);
            }
            float sum = 0.f;
            float e[8];
            #pragma unroll
            for (int j = 0; j < 8; ++j) { e[j] = expf(logits[j] - m); sum += e[j]; }
            float inv = 1.f / sum;
            #pragma unroll
            for (int j = 0; j < 8; ++j) {
                out[b * 8 + j] = logits[j];
                out[1024 + b * 8 + j] = e[j] * inv;
            }
        }
        if (t < 10) out[5244928 + b * 10 + t] = qsel[t];
    }
}

extern "C" void kernel_launch(void* const* d_in, const int* in_sizes, int n_in,
                              void* d_out, int out_size, void* d_ws, size_t ws_size,
                              hipStream_t stream) {
    const float* x      = (const float*)d_in[0];
    const int*   S1     = (const int*)d_in[1];
    const int*   S2     = (const int*)d_in[2];
    const int*   VInum  = (const int*)d_in[3];
    const float* w0     = (const float*)d_in[4];
    const float* b0     = (const float*)d_in[5];
    const float* w_r    = (const float*)d_in[6];
    const float* w_q    = (const float*)d_in[7];
    const float* w_sw   = (const float*)d_in[8];
    const float* w_sw2  = (const float*)d_in[9];
    const float* w_dense= (const float*)d_in[10];
    float* out = (float*)d_out;

    // zero the padded flags (stream-ordered before the kernel; graph-safe)
    hipMemsetAsync(d_ws, 0, 8192 * sizeof(int), stream);
    vin_kernel<<<256, 512, 0, stream>>>(x, S1, S2, VInum, w0, b0, w_r, w_q,
                                        w_sw, w_sw2, w_dense, out, d_ws);
}

// Round 16
// 171.722 us; speedup vs baseline: 2.4975x; 2.4975x over previous
//
#include <hip/hip_runtime.h>
#include <math.h>

// VIN forward on MI355X — single fused kernel, 128 WGs x 1024 thr (16 waves).
// Sizes: N=128, H=W=64, CH_I=2, CH_H=150, CH_Q=10, N_ACT=8, VInum=36.
//
// R25 -> R26 (single change vs R19-best: K-loop nest order d-outer/ap-inner):
//  Cross-WG sync closed for good (R15 390us, R25 359us — two protocol
//  designs, same ~8us/iter intrinsic publish->fence->acquire cost).
//  R19 model: 5600 cyc/SIMD/iter = 1760 VALU (31%, matches) + ~3800 stall
//  from 45 SCATTERED s_load_dwordx2/wave/iter (ap-outer nest strides the
//  weight address by 80B -> 45 independent requests, ~10 free SGPRs ->
//  9+ load->wait->use groups x ~120cyc K$ latency, queued across 16 waves).
//  R21 (8 waves, worse) rules out SQC throughput -> latency-bound chains.
//  Fix: d-outer/ap-inner — for fixed d the 5 pairs are 10 CONTIGUOUS
//  floats (w_sw+d*20+10..19) -> compiler merges to 2-3 wide s_loads per d,
//  arriving together: ~9 tight groups/iter, one wait per d. Each (i,ap)
//  chain still visits d=0..8 ascending, identical floats -> bit-identical.
//  All else R19 verbatim. Pre-committed: null (99-105us) -> structural
//  plateau, stop.

typedef float v2f __attribute__((ext_vector_type(2)));

static __device__ __forceinline__ v2f splat2(float s) { v2f r; r.x = s; r.y = s; return r; }
static __device__ __forceinline__ v2f pkfma(v2f w, float v, v2f a) {
#if __has_builtin(__builtin_elementwise_fma)
    return __builtin_elementwise_fma(w, splat2(v), a);
#else
    v2f r; r.x = fmaf(w.x, v, a.x); r.y = fmaf(w.y, v, a.y); return r;
#endif
}
static __device__ __forceinline__ v2f pkmax(v2f a, v2f b) {
#if __has_builtin(__builtin_elementwise_max)
    return __builtin_elementwise_max(a, b);
#else
    v2f r; r.x = fmaxf(a.x, b.x); r.y = fmaxf(a.y, b.y); return r;
#endif
}

// DPP wave-wide shift by one lane. bound-invalid lanes keep old (=0) ->
// zero halo at lanes 0/63.
#define DPP_SHR1 0x138   // lane n <- lane n-1  (left-neighbor value)
#define DPP_SHL1 0x130   // lane n <- lane n+1  (right-neighbor value)
template <int CTRL>
static __device__ __forceinline__ float dppsh(float v) {
    return __int_as_float(__builtin_amdgcn_update_dpp(
        0, __float_as_int(v), CTRL, 0xF, 0xF, false));
}

#define XROW 69
#define RROW 68                  // rs row stride; idx = (grow+1)*68 + col + 2

__global__ void
__attribute__((amdgpu_flat_work_group_size(1024, 1024)))
__attribute__((amdgpu_waves_per_eu(4, 4)))
vin_kernel(const float* __restrict__ x,
           const int* __restrict__ S1,
           const int* __restrict__ S2,
           const int* __restrict__ VInum,
           const float* __restrict__ w0,
           const float* __restrict__ b0,
           const float* __restrict__ w_r,
           const float* __restrict__ w_q,
           const float* __restrict__ w_sw,
           const float* __restrict__ w_sw2,
           const float* __restrict__ w_dense,
           float* __restrict__ out) {
    const int b = blockIdx.x;
    const int t = threadIdx.x;

    __shared__ float xs0[68 * XROW];     // x ch0, [y+2][x+2], 2-halo of zeros
    __shared__ float xs1[68 * XROW];     // x ch1
    __shared__ float rs[66 * RROW];      // r, pad-2 layout, zero halos
    __shared__ float wtA[1620];          // P chunk partials: 162 entries x 10
    __shared__ float Pp[450];            // P[d][e5x5][ci], zero-init
    __shared__ float Bt[90];             // bias chunk partials
    __shared__ float Bv[9];              // B[d] = w_r[d].b0
    __shared__ float W5c[459];           // 9 classes x (50 weights + bias)
    __shared__ float exT[2][17][64];     // per-wave TOP-row edge, by parity
    __shared__ float exB[2][17][64];     // per-wave BOTTOM-row edge, by parity
    __shared__ float qsel[10];

    // ---- zero LDS (halos/slot-16 must be 0; Pp must be 0) ----
    for (int i = t; i < 68 * XROW; i += 1024) { xs0[i] = 0.f; xs1[i] = 0.f; }
    for (int i = t; i < 66 * RROW; i += 1024) rs[i] = 0.f;
    for (int i = t; i < 2 * 17 * 64; i += 1024) {
        ((float*)exT)[i] = 0.f; ((float*)exB)[i] = 0.f;
    }
    if (t < 450) Pp[t] = 0.f;
    __syncthreads();

    const int row = t >> 4;          // 0..63 (prologue mapping)
    const int cb  = (t & 15) << 2;   // 0,4,...,60

    // ---- stage x (8 contiguous floats = 2x float4 per thread) ----
    {
        const float* xb = x + (size_t)b * 64 * 64 * 2;
        const float4* xp = (const float4*)(xb + (row * 64 + cb) * 2);
        #pragma unroll
        for (int g = 0; g < 2; ++g) {
            float4 v4 = xp[g];
            int px = cb + g * 2;
            xs0[(row + 2) * XROW + px + 2] = v4.x;
            xs1[(row + 2) * XROW + px + 2] = v4.y;
            xs0[(row + 2) * XROW + px + 3] = v4.z;
            xs1[(row + 2) * XROW + px + 3] = v4.w;
        }
    }
    // ---- round A: P chunk partials (1620 items) + bias chunks (90) ----
    for (int idx = t; idx < 1620; idx += 1024) {
        int entry = idx / 10, ch = idx - entry * 10;
        int d = entry / 18, rem = entry % 18;
        int uu = rem >> 1, ci = rem & 1;
        int c0 = ch * 15;
        const float* wr = w_r + d * 150;
        const float* wp = w0 + (uu * 2 + ci) * 150;
        float s = 0.f;
        for (int c = c0; c < c0 + 15; ++c) s += wr[c] * wp[c];
        wtA[idx] = s;
    }
    if (t < 90) {
        int d = t / 10, ch = t - d * 10, c0 = ch * 15;
        float s = 0.f;
        for (int c = c0; c < c0 + 15; ++c) s += w_r[d * 150 + c] * b0[c];
        Bt[t] = s;
    }
    __syncthreads();
    // ---- round B: reduce P entries (162) and B (9) ----
    if (t < 162) {
        float s = 0.f;
        #pragma unroll
        for (int i = 0; i < 10; ++i) s += wtA[t * 10 + i];
        int d = t / 18, rem = t % 18;
        int uu = rem >> 1, ci = rem & 1;
        int dy = d / 3 - 1, dx = d % 3 - 1;
        int uy = uu / 3 - 1, ux = uu % 3 - 1;
        int eidx = (dy + uy + 2) * 5 + (dx + ux + 2);
        Pp[d * 50 + eidx * 2 + ci] = s;
    } else if (t >= 256 && t < 265) {
        int d = t - 256;
        float s = 0.f;
        #pragma unroll
        for (int i = 0; i < 10; ++i) s += Bt[d * 10 + i];
        Bv[d] = s;
    }
    __syncthreads();
    // ---- round C: class subset-sums W5c[9][51] ----
    if (t < 459) {
        int cls = t / 51, j = t - cls * 51;
        int cy = cls / 3, cx = cls % 3;
        float s = 0.f;
        #pragma unroll
        for (int d = 0; d < 9; ++d) {
            int dy = d / 3 - 1, dx = d % 3 - 1;
            bool ok = (cy == 0 || (cy == 1 ? dy >= 0 : dy <= 0)) &&
                      (cx == 0 || (cx == 1 ? dx >= 0 : dx <= 0));
            if (ok) s += (j < 50) ? Pp[d * 50 + j] : Bv[d];
        }
        W5c[t] = s;
    }
    __syncthreads();

    // ---- r everywhere via class-weighted 5x5 stencil (4 px/thread) ----
    {
        int cy = (row == 0) ? 1 : (row == 63) ? 2 : 0;
        #pragma unroll
        for (int p = 0; p < 4; ++p) {
            int xx = cb + p;
            int cx = (xx == 0) ? 1 : (xx == 63) ? 2 : 0;
            const float* Wp = &W5c[(cy * 3 + cx) * 51];
            float acc = Wp[50];
            #pragma unroll
            for (int e = 0; e < 25; ++e) {
                int xi = (row + e / 5) * XROW + (xx + e % 5);
                acc = fmaf(xs0[xi], Wp[e * 2], acc);
                acc = fmaf(xs1[xi], Wp[e * 2 + 1], acc);
            }
            rs[(row + 1) * RROW + xx + 2] = acc;
        }
    }
    __syncthreads();

    // ============ column-per-lane mapping from here on ============
    const int c  = t & 63;           // column 0..63 (lane)
    const int w  = t >> 6;           // wave 0..15, owns rows 4w..4w+3
    const int r0 = w << 2;
    const int upSlot = (w == 0)  ? 16 : w - 1;   // exB[.][upSlot] = row r0-1
    const int dnSlot = (w == 15) ? 16 : w + 1;   // exT[.][dnSlot] = row r0+4
    const int K = VInum[0];

    // ---- Rsw precompute + first step (w_q): r window via DPP ----
    v2f Rsw2[4][5];
    float vprev[4];
    float RC[6], RL[6], RR[6];
    #pragma unroll
    for (int j = 0; j < 6; ++j) RC[j] = rs[(r0 + j) * RROW + c + 2];  // rows r0-1..r0+4
    #pragma unroll
    for (int j = 0; j < 6; ++j) { RL[j] = dppsh<DPP_SHR1>(RC[j]); RR[j] = dppsh<DPP_SHL1>(RC[j]); }
    {
        float vmax[4];
        #pragma unroll
        for (int a = 0; a < 10; ++a) {
            #pragma unroll
            for (int i = 0; i < 4; ++i) {
                float accR = 0.f, accQ = 0.f;
                #pragma unroll
                for (int d = 0; d < 9; ++d) {
                    const int dy = d / 3, dx = d % 3;
                    const float rv = (dx == 0 ? RL : dx == 1 ? RC : RR)[i + dy];
                    accR = fmaf(w_sw[d * 20 + a], rv, accR);
                    accQ = fmaf(w_q[d * 20 + a],  rv, accQ);
                }
                if (a & 1) Rsw2[i][a >> 1].y = accR; else Rsw2[i][a >> 1].x = accR;
                vmax[i] = (a == 0) ? accQ : fmaxf(vmax[i], accQ);
            }
        }
        exT[1][w][c] = vmax[0];          // v^1 edges, parity 1
        exB[1][w][c] = vmax[3];
        #pragma unroll
        for (int i = 0; i < 4; ++i) vprev[i] = vmax[i];
    }
    __syncthreads();

    // ---- K-1 shared-weight VI steps: d-outer nest, contiguous weight loads ----
    for (int k = 2; k <= K; ++k) {
        const int pr = (k - 1) & 1, pw = k & 1;
        float VC[6], VL[6], VR[6];
        VC[0] = exB[pr][upSlot][c];      // row r0-1 (neighbor wave / halo 0)
        VC[5] = exT[pr][dnSlot][c];      // row r0+4
        #pragma unroll
        for (int i = 0; i < 4; ++i) VC[i + 1] = vprev[i];
        #pragma unroll
        for (int j = 0; j < 6; ++j) { VL[j] = dppsh<DPP_SHR1>(VC[j]); VR[j] = dppsh<DPP_SHL1>(VC[j]); }

        v2f acc[4][5];
        #pragma unroll
        for (int d = 0; d < 9; ++d) {
            // 10 CONTIGUOUS floats for this d -> compiler merges into wide
            // s_loads, one wait per d (was 45 scattered dwordx2 per iter)
            const float* wp = w_sw + d * 20 + 10;
            v2f wd0, wd1, wd2, wd3, wd4;
            wd0.x = wp[0]; wd0.y = wp[1];
            wd1.x = wp[2]; wd1.y = wp[3];
            wd2.x = wp[4]; wd2.y = wp[5];
            wd3.x = wp[6]; wd3.y = wp[7];
            wd4.x = wp[8]; wd4.y = wp[9];
            const int dy = d / 3, dx = d % 3;
            const float* S = (dx == 0) ? VL : (dx == 1) ? VC : VR;
            #pragma unroll
            for (int i = 0; i < 4; ++i) {
                const float sv = S[i + dy];
                if (d == 0) {
                    acc[i][0] = pkfma(wd0, sv, Rsw2[i][0]);
                    acc[i][1] = pkfma(wd1, sv, Rsw2[i][1]);
                    acc[i][2] = pkfma(wd2, sv, Rsw2[i][2]);
                    acc[i][3] = pkfma(wd3, sv, Rsw2[i][3]);
                    acc[i][4] = pkfma(wd4, sv, Rsw2[i][4]);
                } else {
                    acc[i][0] = pkfma(wd0, sv, acc[i][0]);
                    acc[i][1] = pkfma(wd1, sv, acc[i][1]);
                    acc[i][2] = pkfma(wd2, sv, acc[i][2]);
                    acc[i][3] = pkfma(wd3, sv, acc[i][3]);
                    acc[i][4] = pkfma(wd4, sv, acc[i][4]);
                }
            }
        }
        float vnew[4];
        #pragma unroll
        for (int i = 0; i < 4; ++i) {
            v2f m2 = acc[i][0];
            #pragma unroll
            for (int ap = 1; ap < 5; ++ap) m2 = pkmax(m2, acc[i][ap]);
            vnew[i] = fmaxf(m2.x, m2.y);
        }
        exT[pw][w][c] = vnew[0];         // publish v^k edges
        exB[pw][w][c] = vnew[3];
        #pragma unroll
        for (int i = 0; i < 4; ++i) vprev[i] = vnew[i];
        __syncthreads();
    }

    // ---- final step with w_sw2: q -> global, gather (S1,S2) ----
    const int s1 = S1[b], s2 = S2[b];
    {
        const int pK = K & 1;
        float VC[6], VL[6], VR[6];
        VC[0] = exB[pK][upSlot][c];
        VC[5] = exT[pK][dnSlot][c];
        #pragma unroll
        for (int i = 0; i < 4; ++i) VC[i + 1] = vprev[i];
        #pragma unroll
        for (int j = 0; j < 6; ++j) { VL[j] = dppsh<DPP_SHR1>(VC[j]); VR[j] = dppsh<DPP_SHL1>(VC[j]); }

        float qv[4][10];
        #pragma unroll
        for (int a = 0; a < 10; ++a) {
            #pragma unroll
            for (int i = 0; i < 4; ++i) {
                float acc = 0.f;
                #pragma unroll
                for (int d = 0; d < 9; ++d) {
                    const int dy = d / 3, dx = d % 3;
                    acc = fmaf(w_sw2[d * 20 + a],
                               (dx == 0 ? RL : dx == 1 ? RC : RR)[i + dy], acc);
                    acc = fmaf(w_sw2[d * 20 + 10 + a],
                               (dx == 0 ? VL : dx == 1 ? VC : VR)[i + dy], acc);
                }
                qv[i][a] = acc;
            }
        }
        // store q: 10 floats per px, 8B-aligned -> 5x float2 per row
        #pragma unroll
        for (int i = 0; i < 4; ++i) {
            float2* qp = (float2*)(out + 2048 +
                          ((size_t)((b * 64 + r0 + i) * 64 + c)) * 10);
            #pragma unroll
            for (int g = 0; g < 5; ++g)
                qp[g] = make_float2(qv[i][2 * g], qv[i][2 * g + 1]);
        }
        if (c == s2) {
            #pragma unroll
            for (int i = 0; i < 4; ++i)
                if (s1 == r0 + i) {
                    #pragma unroll
                    for (int a = 0; a < 10; ++a) qsel[a] = qv[i][a];
                }
        }
    }
    __syncthreads();

    // ---- dense + softmax (thread 0), q_out (threads 0..9) ----
    if (t == 0) {
        float logits[8];
        float m = -1e30f;
        #pragma unroll
        for (int j = 0; j < 8; ++j) {
            float s = 0.f;
            #pragma unroll
            for (int a = 0; a < 10; ++a) s += qsel[a] * w_dense[a * 8 + j];
            logits[j] = s;
            m = fmaxf(m, s);
        }
        float sum = 0.f;
        float e[8];
        #pragma unroll
        for (int j = 0; j < 8; ++j) { e[j] = expf(logits[j] - m); sum += e[j]; }
        float inv = 1.f / sum;
        #pragma unroll
        for (int j = 0; j < 8; ++j) {
            out[b * 8 + j] = logits[j];
            out[1024 + b * 8 + j] = e[j] * inv;
        }
    }
    if (t < 10) out[5244928 + b * 10 + t] = qsel[t];
}

extern "C" void kernel_launch(void* const* d_in, const int* in_sizes, int n_in,
                              void* d_out, int out_size, void* d_ws, size_t ws_size,
                              hipStream_t stream) {
    const float* x      = (const float*)d_in[0];
    const int*   S1     = (const int*)d_in[1];
    const int*   S2     = (const int*)d_in[2];
    const int*   VInum  = (const int*)d_in[3];
    const float* w0     = (const float*)d_in[4];
    const float* b0     = (const float*)d_in[5];
    const float* w_r    = (const float*)d_in[6];
    const float* w_q    = (const float*)d_in[7];
    const float* w_sw   = (const float*)d_in[8];
    const float* w_sw2  = (const float*)d_in[9];
    const float* w_dense= (const float*)d_in[10];
    float* out = (float*)d_out;

    vin_kernel<<<128, 1024, 0, stream>>>(x, S1, S2, VInum, w0, b0, w_r, w_q,
                                         w_sw, w_sw2, w_dense, out);
}